// Round 12
// baseline (28.135 us; speedup 1.0000x reference)
//
#include <hip/hip_runtime.h>
#include <hip/hip_fp16.h>

#define N 2048
#define IN_DIM 128
#define D 64
#define ALPHA 0.2f
#define TI 4
#define BLK 512
#define NW (BLK / 64)   // 8 waves per block
#define PN (N + 16)     // p_lds row stride (shorts): 4128 B -> 2-way (free)

// e[i,j] = b_i + b_j + sum_d 0.4*a_d*|Wh[i,d]+Wh[j,d]|,  b_i = 0.6*dot(a,Wh_i)
// Softmax invariances: b_i dropped (per-row constant), p scaled by 2^-6.
// bs2[j] = 0.6*dot(a,Wh_j)*log2(e) - 6 precomputed -> phase 2 is fma+exp2.
// R10: PV on the matrix pipe (v_mfma_f32_16x16x32_f16), 8 K-steps x 4 d-tiles.
// R11: B-fragments pre-tiled (WhB[jp>>2][d][jp&3]) -> one b128/fragment.
// R12: wh H-operand scalarized (readfirstlane -> s_load; kills 64 ds_read
// + hl staging); p_lds padded to N+16 (4-way -> 2-way A-fragment reads).

typedef _Float16 half2v __attribute__((ext_vector_type(2)));
typedef _Float16 half8 __attribute__((ext_vector_type(8)));
typedef float f32x4 __attribute__((ext_vector_type(4)));

__device__ __forceinline__ unsigned short f2h_rne(float f) {
  return __half_as_ushort(__float2half(f));
}

__device__ __forceinline__ float dot2abs(unsigned s2, unsigned w2,
                                         unsigned a2, float acc) {
  half2v sv = __builtin_bit_cast(half2v, s2);
  half2v wv = __builtin_bit_cast(half2v, w2);
  half2v t = sv + wv;                                   // v_pk_add_f16
  unsigned tu = __builtin_bit_cast(unsigned, t) & 0x7fff7fffu;  // packed abs
  return __builtin_amdgcn_fdot2(__builtin_bit_cast(half2v, tu),
                                __builtin_bit_cast(half2v, a2),
                                acc, false);            // v_dot2_f32_f16
}

__device__ __forceinline__ unsigned cvt_pk_u(float lo, float hi) {
  return __builtin_bit_cast(unsigned, __builtin_amdgcn_cvt_pkrtz(lo, hi));
}

// Kernel 1: 512 threads, 4 rows/block, split-K (2 thr/output).
// Whh f16 [N,D], WhP u32 [D/2][N] d-pairs transposed (phase-1 stream),
// WhB u32 [N/8][D][4] MFMA-fragment-tiled row-pairs (phase-3 B operand),
// bs2[j] = 0.6*dot(a,Wh_j)*L2E - 6, ap2 = packed 0.4*a.
__global__ __launch_bounds__(512) void wh_kernel(
    const float* __restrict__ H, const float* __restrict__ W,
    const float* __restrict__ a, unsigned short* __restrict__ Whh,
    unsigned int* __restrict__ WhP, unsigned int* __restrict__ WhB,
    float* __restrict__ bs2, unsigned int* __restrict__ ap2) {
  __shared__ float wlds[D][IN_DIM + 1];          // 33 KB
  __shared__ float partial[512];
  __shared__ __align__(16) unsigned short hh[4][D];
  const int t = threadIdx.x;
  const int i0 = blockIdx.x * 4;
  const float L2E = 1.4426950408889634f;

  if (blockIdx.x == 0 && t < D / 2) {
    ap2[t] = (unsigned)f2h_rne(0.4f * a[2 * t]) |
             ((unsigned)f2h_rne(0.4f * a[2 * t + 1]) << 16);
  }

  #pragma unroll
  for (int rep = 0; rep < 4; ++rep) {
    int idx = (rep * 512 + t) * 4;               // covers 0..8191
    float4 w4 = *(const float4*)&W[idx];
    int d = idx >> 7, k = idx & 127;
    wlds[d][k] = w4.x; wlds[d][k + 1] = w4.y;
    wlds[d][k + 2] = w4.z; wlds[d][k + 3] = w4.w;
  }
  __syncthreads();

  {
    // r, kh are wave-uniform: force SGPR -> H reads become s_load
    // (scalar pipe), halving the inner loop's LDS traffic.
    const int rs = __builtin_amdgcn_readfirstlane((t & 255) >> 6);
    const int khs = __builtin_amdgcn_readfirstlane(t >> 8);
    const int d = t & 63;
    const float* __restrict__ hp = H + (i0 + rs) * IN_DIM + khs * 64;
    float acc = 0.f;
    #pragma unroll 8
    for (int k = 0; k < 64; ++k)
      acc = fmaf(hp[k], wlds[d][khs * 64 + k], acc);
    partial[t] = acc;
  }
  __syncthreads();

  if (t < 256) {
    const int r = t >> 6, d = t & 63;
    const float acc = partial[t] + partial[t + 256];
    const unsigned myh = f2h_rne(acc);
    hh[r][d] = (unsigned short)myh;
    Whh[(i0 + r) * D + d] = (unsigned short)myh;
    const unsigned hq = (unsigned)__shfl_xor((int)myh, 1);
    if (!(d & 1)) WhP[(d >> 1) * N + (i0 + r)] = myh | (hq << 16);
    float pb = a[d] * acc;
    #pragma unroll
    for (int off = 32; off; off >>= 1) pb += __shfl_xor(pb, off);
    if (d == 0) bs2[i0 + r] = fmaf(0.6f * pb, L2E, -6.f);
  }
  __syncthreads();                               // hh complete
  if (t < 128) {
    const int pr = t >> 6, d = t & 63;           // pairs (0,1),(2,3)
    const unsigned lo = hh[pr * 2][d], hi = hh[pr * 2 + 1][d];
    const int jp = (i0 >> 1) + pr;               // j-pair index
    WhB[(jp >> 2) * (D * 4) + d * 4 + (jp & 3)] = lo | (hi << 16);
  }
}

// Kernel 2: fused e -> exp -> sum -> PV(MFMA). 512 threads, TI=4, 4 j/thread.
__global__ __launch_bounds__(BLK, 4) void attn_kernel(
    const unsigned short* __restrict__ Whh,
    const unsigned int* __restrict__ WhP,
    const unsigned int* __restrict__ WhB,
    const float* __restrict__ bs2, const unsigned int* __restrict__ ap2,
    float* __restrict__ out) {
  __shared__ unsigned short p_lds[TI][PN];  // f16 p (x 2^-6), padded rows
  __shared__ float red2s[TI][NW];
  __shared__ float part[NW][TI][D];         // 8 KB
  __shared__ uint4 stage[TI * 8 + D / 8];   // 640 B: Whh rows + ap2

  const int t = threadIdx.x;
  const int i0 = blockIdx.x * TI;
  const int wid = t >> 6, lane = t & 63;

  // Stage block-uniform operands once
  if (t < TI * 8 + D / 8) {
    stage[t] = (t < TI * 8) ? ((const uint4*)(Whh + i0 * D))[t]
                            : ((const uint4*)ap2)[t - TI * 8];
  }
  __syncthreads();

  // ---- Phase 1: e row-block (512 thr x 4 j), packed-f16 dot2 core ----
  const int j0 = t * 4;
  float4 bj = *(const float4*)&bs2[j0];
  float4 ac[TI];
  #pragma unroll
  for (int ti = 0; ti < TI; ++ti) { ac[ti].x = ac[ti].y = ac[ti].z = ac[ti].w = 0.f; }

  const unsigned int* wp = WhP + j0;      // column j0 stream, stride N

  uint4 wbuf[2][4], sbuf[2][TI], abuf[2];
  #pragma unroll
  for (int q = 0; q < 4; ++q) wbuf[0][q] = *(const uint4*)&wp[q * N];
  #pragma unroll
  for (int ti = 0; ti < TI; ++ti) sbuf[0][ti] = stage[ti * 8];  // LDS broadcast
  abuf[0] = stage[TI * 8];

  #pragma unroll
  for (int c = 0; c < D / 8; ++c) {       // 8 chunks of 4 d-pairs (8 d's)
    const int cur = c & 1, nxt = cur ^ 1;
    if (c < D / 8 - 1) {
      #pragma unroll
      for (int q = 0; q < 4; ++q)
        wbuf[nxt][q] = *(const uint4*)&wp[((c + 1) * 4 + q) * N];
      #pragma unroll
      for (int ti = 0; ti < TI; ++ti) sbuf[nxt][ti] = stage[ti * 8 + c + 1];
      abuf[nxt] = stage[TI * 8 + c + 1];
    }
    #pragma unroll
    for (int q = 0; q < 4; ++q) {
      const unsigned a2 = (q == 0) ? abuf[cur].x : (q == 1) ? abuf[cur].y
                        : (q == 2) ? abuf[cur].z : abuf[cur].w;
      const uint4 w4 = wbuf[cur][q];
      #pragma unroll
      for (int ti = 0; ti < TI; ++ti) {
        const unsigned s2 = (q == 0) ? sbuf[cur][ti].x : (q == 1) ? sbuf[cur][ti].y
                          : (q == 2) ? sbuf[cur][ti].z : sbuf[cur][ti].w;
        ac[ti].x = dot2abs(s2, w4.x, a2, ac[ti].x);
        ac[ti].y = dot2abs(s2, w4.y, a2, ac[ti].y);
        ac[ti].z = dot2abs(s2, w4.z, a2, ac[ti].z);
        ac[ti].w = dot2abs(s2, w4.w, a2, ac[ti].w);
      }
    }
  }

  // Phase-3 geometry + hoisted ks=0 B-fragments (b128 from WhB; latency
  // hides under phase 2 + barrier convergence).
  const int kbase = wid * (N / NW);            // 256 j's per wave
  const int arow = lane & 3;                   // p_lds row (ti, aliased mod 4)
  const int koff = (lane >> 4) * 8;            // k-group within the 32-slice
  const int bcol = lane & 15;                  // d within tile
  const int brow0 = (lane >> 4) * 4;           // j-pair group (multiple of 4)
  const int jp0 = (kbase >> 1) + brow0;        // aligned to 4
  uint4 bq0[4];
  #pragma unroll
  for (int dt = 0; dt < 4; ++dt)
    bq0[dt] = *(const uint4*)&WhB[(jp0 >> 2) * (D * 4) + (dt * 16 + bcol) * 4];

  // ---- Phase 2: p = exp2(ac*L2E + bs2_j); store packed f16 pairs ----
  const float L2E = 1.4426950408889634f;
  float s_t[TI];
  #pragma unroll
  for (int ti = 0; ti < TI; ++ti) {
    float4 p4;
    p4.x = __builtin_amdgcn_exp2f(fmaf(ac[ti].x, L2E, bj.x));
    p4.y = __builtin_amdgcn_exp2f(fmaf(ac[ti].y, L2E, bj.y));
    p4.z = __builtin_amdgcn_exp2f(fmaf(ac[ti].z, L2E, bj.z));
    p4.w = __builtin_amdgcn_exp2f(fmaf(ac[ti].w, L2E, bj.w));
    uint2 ph;
    ph.x = cvt_pk_u(p4.x, p4.y);   // pairs (j0, j0+1): even j lo
    ph.y = cvt_pk_u(p4.z, p4.w);
    *(uint2*)&p_lds[ti][j0] = ph;
    s_t[ti] = (p4.x + p4.y) + (p4.z + p4.w);
  }
  #pragma unroll
  for (int off = 32; off; off >>= 1) {
    #pragma unroll
    for (int ti = 0; ti < TI; ++ti)
      s_t[ti] += __shfl_xor(s_t[ti], off);
  }
  if (lane == 0) {
    #pragma unroll
    for (int ti = 0; ti < TI; ++ti) red2s[ti][wid] = s_t[ti];
  }
  __syncthreads();   // publishes p_lds + red2s

  // ---- Phase 3: out = (p @ Wh) / rowsum via mfma_f32_16x16x32_f16 ----
  // A: free dim = rows(i), k = (lane>>4)*8 + e; one b128 LDS read/K-step.
  // B: free dim = cols(d) = lane&15; reg r = j-pair -- WhB tile's 4 u32.
  // D: col = lane&15, row = (lane>>4)*4 + reg.
  f32x4 acc[4];
  #pragma unroll
  for (int dt = 0; dt < 4; ++dt) acc[dt] = (f32x4){0.f, 0.f, 0.f, 0.f};

  #pragma unroll
  for (int ks = 0; ks < 8; ++ks) {             // 8 K-steps of 32 j's
    const int jlo = kbase + ks * 32;
    const uint4 av = *(const uint4*)&p_lds[arow][jlo + koff];
    const half8 a8 = __builtin_bit_cast(half8, av);
    const unsigned tb = ((jp0 + ks * 16) >> 2) * (D * 4) + bcol * 4;
    #pragma unroll
    for (int dt = 0; dt < 4; ++dt) {
      const uint4 bv = (ks == 0) ? bq0[dt]
                     : *(const uint4*)&WhB[tb + dt * 64];
      acc[dt] = __builtin_amdgcn_mfma_f32_16x16x32_f16(
          a8, __builtin_bit_cast(half8, bv), acc[dt], 0, 0, 0);
    }
  }

  // C rows 0-3 live in lanes 0-15 (lane>>4 == 0), reg index = row = ti.
  if (lane < 16) {
    #pragma unroll
    for (int dt = 0; dt < 4; ++dt) {
      #pragma unroll
      for (int r = 0; r < 4; ++r)
        part[wid][r][dt * 16 + lane] = acc[dt][r];
    }
  }
  __syncthreads();
  if (t < TI * D) {
    const int ti = t >> 6, dd = t & 63;
    float s = 0.f;
    #pragma unroll
    for (int w = 0; w < NW; ++w) s += part[w][ti][dd];
    float4 r0 = *(const float4*)&red2s[ti][0];
    float4 r1 = *(const float4*)&red2s[ti][4];
    float rsum = ((r0.x + r0.y) + (r0.z + r0.w)) +
                 ((r1.x + r1.y) + (r1.z + r1.w));
    out[(i0 + ti) * D + dd] = s * (1.f / rsum);
  }
}

extern "C" void kernel_launch(void* const* d_in, const int* in_sizes, int n_in,
                              void* d_out, int out_size, void* d_ws, size_t ws_size,
                              hipStream_t stream) {
  const float* H = (const float*)d_in[0];
  const float* W = (const float*)d_in[1];
  const float* a = (const float*)d_in[2];
  float* out = (float*)d_out;

  unsigned short* Whh = (unsigned short*)d_ws;          // N*D f16
  unsigned int* WhP = (unsigned int*)(Whh + N * D);     // (D/2)*N u32 f16 d-pairs
  unsigned int* WhB = WhP + (D / 2) * N;                // (N/8)*D*4 u32 tiled pairs
  float* bs2 = (float*)(WhB + (N / 8) * D * 4);         // N (log2-domain bias)
  unsigned int* ap2 = (unsigned int*)(bs2 + N);         // D/2

  wh_kernel<<<N / 4, 512, 0, stream>>>(H, W, a, Whh, WhP, WhB, bs2, ap2);
  attn_kernel<<<N / TI, BLK, 0, stream>>>(Whh, WhP, WhB, bs2, ap2, out);
}

// Round 13
// 27.724 us; speedup vs baseline: 1.0148x; 1.0148x over previous
//
#include <hip/hip_runtime.h>
#include <hip/hip_fp16.h>

#define N 2048
#define IN_DIM 128
#define D 64
#define ALPHA 0.2f
#define TI 4
#define BLK 512
#define NW (BLK / 64)   // 8 waves per block

// e[i,j] = b_i + b_j + sum_d 0.4*a_d*|Wh[i,d]+Wh[j,d]|,  b_i = 0.6*dot(a,Wh_i)
// Softmax invariances: b_i dropped (per-row constant), p scaled by 2^-6.
// bs2[j] = 0.6*dot(a,Wh_j)*log2(e) - 6 precomputed -> phase 2 is fma+exp2.
// R10: PV on the matrix pipe (v_mfma_f32_16x16x32_f16), wave w owns K-slice
// [w*256,(w+1)*256): 8 K-steps x 4 d-tiles = 32 MFMA.
// R11 (best measured, 27.93 us): B-fragments pre-tiled in memory:
// WhB[jp>>2][d][jp&3] (1KB tiles) -> one b128 load per (ks,dt) instead of
// 4 stride-D dword gathers. R12's extra edits (wh s_load + p_lds pad)
// measured neutral-negative -> reverted.

typedef _Float16 half2v __attribute__((ext_vector_type(2)));
typedef _Float16 half8 __attribute__((ext_vector_type(8)));
typedef float f32x4 __attribute__((ext_vector_type(4)));

__device__ __forceinline__ unsigned short f2h_rne(float f) {
  return __half_as_ushort(__float2half(f));
}

__device__ __forceinline__ float dot2abs(unsigned s2, unsigned w2,
                                         unsigned a2, float acc) {
  half2v sv = __builtin_bit_cast(half2v, s2);
  half2v wv = __builtin_bit_cast(half2v, w2);
  half2v t = sv + wv;                                   // v_pk_add_f16
  unsigned tu = __builtin_bit_cast(unsigned, t) & 0x7fff7fffu;  // packed abs
  return __builtin_amdgcn_fdot2(__builtin_bit_cast(half2v, tu),
                                __builtin_bit_cast(half2v, a2),
                                acc, false);            // v_dot2_f32_f16
}

__device__ __forceinline__ unsigned cvt_pk_u(float lo, float hi) {
  return __builtin_bit_cast(unsigned, __builtin_amdgcn_cvt_pkrtz(lo, hi));
}

// Kernel 1: 512 threads, 4 rows/block, split-K (2 thr/output).
// Whh f16 [N,D], WhP u32 [D/2][N] d-pairs transposed (phase-1 stream),
// WhB u32 [N/8][D][4] MFMA-fragment-tiled row-pairs (phase-3 B operand),
// bs2[j] = 0.6*dot(a,Wh_j)*L2E - 6, ap2 = packed 0.4*a.
__global__ __launch_bounds__(512) void wh_kernel(
    const float* __restrict__ H, const float* __restrict__ W,
    const float* __restrict__ a, unsigned short* __restrict__ Whh,
    unsigned int* __restrict__ WhP, unsigned int* __restrict__ WhB,
    float* __restrict__ bs2, unsigned int* __restrict__ ap2) {
  __shared__ float wlds[D][IN_DIM + 1];          // 33 KB
  __shared__ float hl[4 * IN_DIM];
  __shared__ float partial[512];
  __shared__ __align__(16) unsigned short hh[4][D];
  const int t = threadIdx.x;
  const int i0 = blockIdx.x * 4;
  const float L2E = 1.4426950408889634f;

  if (blockIdx.x == 0 && t < D / 2) {
    ap2[t] = (unsigned)f2h_rne(0.4f * a[2 * t]) |
             ((unsigned)f2h_rne(0.4f * a[2 * t + 1]) << 16);
  }

  #pragma unroll
  for (int rep = 0; rep < 4; ++rep) {
    int idx = (rep * 512 + t) * 4;               // covers 0..8191
    float4 w4 = *(const float4*)&W[idx];
    int d = idx >> 7, k = idx & 127;
    wlds[d][k] = w4.x; wlds[d][k + 1] = w4.y;
    wlds[d][k + 2] = w4.z; wlds[d][k + 3] = w4.w;
  }
  if (t < 128)
    *(float4*)&hl[t * 4] = *(const float4*)&H[i0 * IN_DIM + t * 4];
  __syncthreads();

  {
    const int oi = t & 255, kh = t >> 8;         // 2 threads per output
    const int r = oi >> 6, d = oi & 63;
    float acc = 0.f;
    #pragma unroll 8
    for (int k = 0; k < 64; ++k)
      acc = fmaf(hl[r * IN_DIM + kh * 64 + k], wlds[d][kh * 64 + k], acc);
    partial[t] = acc;
  }
  __syncthreads();

  if (t < 256) {
    const int r = t >> 6, d = t & 63;
    const float acc = partial[t] + partial[t + 256];
    const unsigned myh = f2h_rne(acc);
    hh[r][d] = (unsigned short)myh;
    Whh[(i0 + r) * D + d] = (unsigned short)myh;
    const unsigned hq = (unsigned)__shfl_xor((int)myh, 1);
    if (!(d & 1)) WhP[(d >> 1) * N + (i0 + r)] = myh | (hq << 16);
    float pb = a[d] * acc;
    #pragma unroll
    for (int off = 32; off; off >>= 1) pb += __shfl_xor(pb, off);
    if (d == 0) bs2[i0 + r] = fmaf(0.6f * pb, L2E, -6.f);
  }
  __syncthreads();                               // hh complete
  if (t < 128) {
    const int pr = t >> 6, d = t & 63;           // pairs (0,1),(2,3)
    const unsigned lo = hh[pr * 2][d], hi = hh[pr * 2 + 1][d];
    const int jp = (i0 >> 1) + pr;               // j-pair index
    WhB[(jp >> 2) * (D * 4) + d * 4 + (jp & 3)] = lo | (hi << 16);
  }
}

// Kernel 2: fused e -> exp -> sum -> PV(MFMA). 512 threads, TI=4, 4 j/thread.
__global__ __launch_bounds__(BLK, 4) void attn_kernel(
    const unsigned short* __restrict__ Whh,
    const unsigned int* __restrict__ WhP,
    const unsigned int* __restrict__ WhB,
    const float* __restrict__ bs2, const unsigned int* __restrict__ ap2,
    float* __restrict__ out) {
  __shared__ unsigned short p_lds[TI][N];  // 16 KB, f16 (scaled by 2^-6)
  __shared__ float red2s[TI][NW];
  __shared__ float part[NW][TI][D];        // 8 KB
  __shared__ uint4 stage[TI * 8 + D / 8];  // 640 B: Whh rows + ap2

  const int t = threadIdx.x;
  const int i0 = blockIdx.x * TI;
  const int wid = t >> 6, lane = t & 63;

  // Stage block-uniform operands once
  if (t < TI * 8 + D / 8) {
    stage[t] = (t < TI * 8) ? ((const uint4*)(Whh + i0 * D))[t]
                            : ((const uint4*)ap2)[t - TI * 8];
  }
  __syncthreads();

  // ---- Phase 1: e row-block (512 thr x 4 j), packed-f16 dot2 core ----
  const int j0 = t * 4;
  float4 bj = *(const float4*)&bs2[j0];
  float4 ac[TI];
  #pragma unroll
  for (int ti = 0; ti < TI; ++ti) { ac[ti].x = ac[ti].y = ac[ti].z = ac[ti].w = 0.f; }

  const unsigned int* wp = WhP + j0;      // column j0 stream, stride N

  uint4 wbuf[2][4], sbuf[2][TI], abuf[2];
  #pragma unroll
  for (int q = 0; q < 4; ++q) wbuf[0][q] = *(const uint4*)&wp[q * N];
  #pragma unroll
  for (int ti = 0; ti < TI; ++ti) sbuf[0][ti] = stage[ti * 8];  // LDS broadcast
  abuf[0] = stage[TI * 8];

  #pragma unroll
  for (int c = 0; c < D / 8; ++c) {       // 8 chunks of 4 d-pairs (8 d's)
    const int cur = c & 1, nxt = cur ^ 1;
    if (c < D / 8 - 1) {
      #pragma unroll
      for (int q = 0; q < 4; ++q)
        wbuf[nxt][q] = *(const uint4*)&wp[((c + 1) * 4 + q) * N];
      #pragma unroll
      for (int ti = 0; ti < TI; ++ti) sbuf[nxt][ti] = stage[ti * 8 + c + 1];
      abuf[nxt] = stage[TI * 8 + c + 1];
    }
    #pragma unroll
    for (int q = 0; q < 4; ++q) {
      const unsigned a2 = (q == 0) ? abuf[cur].x : (q == 1) ? abuf[cur].y
                        : (q == 2) ? abuf[cur].z : abuf[cur].w;
      const uint4 w4 = wbuf[cur][q];
      #pragma unroll
      for (int ti = 0; ti < TI; ++ti) {
        const unsigned s2 = (q == 0) ? sbuf[cur][ti].x : (q == 1) ? sbuf[cur][ti].y
                          : (q == 2) ? sbuf[cur][ti].z : sbuf[cur][ti].w;
        ac[ti].x = dot2abs(s2, w4.x, a2, ac[ti].x);
        ac[ti].y = dot2abs(s2, w4.y, a2, ac[ti].y);
        ac[ti].z = dot2abs(s2, w4.z, a2, ac[ti].z);
        ac[ti].w = dot2abs(s2, w4.w, a2, ac[ti].w);
      }
    }
  }

  // Phase-3 geometry + hoisted ks=0 B-fragments (b128 from WhB; latency
  // hides under phase 2 + barrier convergence).
  const int kbase = wid * (N / NW);            // 256 j's per wave
  const int arow = lane & 3;                   // p_lds row (ti, aliased mod 4)
  const int koff = (lane >> 4) * 8;            // k-group within the 32-slice
  const int bcol = lane & 15;                  // d within tile
  const int brow0 = (lane >> 4) * 4;           // j-pair group (multiple of 4)
  const int jp0 = (kbase >> 1) + brow0;        // aligned to 4
  uint4 bq0[4];
  #pragma unroll
  for (int dt = 0; dt < 4; ++dt)
    bq0[dt] = *(const uint4*)&WhB[(jp0 >> 2) * (D * 4) + (dt * 16 + bcol) * 4];

  // ---- Phase 2: p = exp2(ac*L2E + bs2_j); store packed f16 pairs ----
  const float L2E = 1.4426950408889634f;
  float s_t[TI];
  #pragma unroll
  for (int ti = 0; ti < TI; ++ti) {
    float4 p4;
    p4.x = __builtin_amdgcn_exp2f(fmaf(ac[ti].x, L2E, bj.x));
    p4.y = __builtin_amdgcn_exp2f(fmaf(ac[ti].y, L2E, bj.y));
    p4.z = __builtin_amdgcn_exp2f(fmaf(ac[ti].z, L2E, bj.z));
    p4.w = __builtin_amdgcn_exp2f(fmaf(ac[ti].w, L2E, bj.w));
    uint2 ph;
    ph.x = cvt_pk_u(p4.x, p4.y);   // pairs (j0, j0+1): even j lo
    ph.y = cvt_pk_u(p4.z, p4.w);
    *(uint2*)&p_lds[ti][j0] = ph;
    s_t[ti] = (p4.x + p4.y) + (p4.z + p4.w);
  }
  #pragma unroll
  for (int off = 32; off; off >>= 1) {
    #pragma unroll
    for (int ti = 0; ti < TI; ++ti)
      s_t[ti] += __shfl_xor(s_t[ti], off);
  }
  if (lane == 0) {
    #pragma unroll
    for (int ti = 0; ti < TI; ++ti) red2s[ti][wid] = s_t[ti];
  }
  __syncthreads();   // publishes p_lds + red2s

  // ---- Phase 3: out = (p @ Wh) / rowsum via mfma_f32_16x16x32_f16 ----
  // A: free dim = rows(i), k = (lane>>4)*8 + e; one b128 LDS read/K-step.
  // B: free dim = cols(d) = lane&15; reg r = j-pair -- WhB tile's 4 u32.
  // D: col = lane&15, row = (lane>>4)*4 + reg.
  f32x4 acc[4];
  #pragma unroll
  for (int dt = 0; dt < 4; ++dt) acc[dt] = (f32x4){0.f, 0.f, 0.f, 0.f};

  #pragma unroll
  for (int ks = 0; ks < 8; ++ks) {             // 8 K-steps of 32 j's
    const int jlo = kbase + ks * 32;
    const uint4 av = *(const uint4*)&p_lds[arow][jlo + koff];
    const half8 a8 = __builtin_bit_cast(half8, av);
    const unsigned tb = ((jp0 + ks * 16) >> 2) * (D * 4) + bcol * 4;
    #pragma unroll
    for (int dt = 0; dt < 4; ++dt) {
      const uint4 bv = (ks == 0) ? bq0[dt]
                     : *(const uint4*)&WhB[tb + dt * 64];
      acc[dt] = __builtin_amdgcn_mfma_f32_16x16x32_f16(
          a8, __builtin_bit_cast(half8, bv), acc[dt], 0, 0, 0);
    }
  }

  // C rows 0-3 live in lanes 0-15 (lane>>4 == 0), reg index = row = ti.
  if (lane < 16) {
    #pragma unroll
    for (int dt = 0; dt < 4; ++dt) {
      #pragma unroll
      for (int r = 0; r < 4; ++r)
        part[wid][r][dt * 16 + lane] = acc[dt][r];
    }
  }
  __syncthreads();
  if (t < TI * D) {
    const int ti = t >> 6, dd = t & 63;
    float s = 0.f;
    #pragma unroll
    for (int w = 0; w < NW; ++w) s += part[w][ti][dd];
    float4 r0 = *(const float4*)&red2s[ti][0];
    float4 r1 = *(const float4*)&red2s[ti][4];
    float rsum = ((r0.x + r0.y) + (r0.z + r0.w)) +
                 ((r1.x + r1.y) + (r1.z + r1.w));
    out[(i0 + ti) * D + dd] = s * (1.f / rsum);
  }
}

extern "C" void kernel_launch(void* const* d_in, const int* in_sizes, int n_in,
                              void* d_out, int out_size, void* d_ws, size_t ws_size,
                              hipStream_t stream) {
  const float* H = (const float*)d_in[0];
  const float* W = (const float*)d_in[1];
  const float* a = (const float*)d_in[2];
  float* out = (float*)d_out;

  unsigned short* Whh = (unsigned short*)d_ws;          // N*D f16
  unsigned int* WhP = (unsigned int*)(Whh + N * D);     // (D/2)*N u32 f16 d-pairs
  unsigned int* WhB = WhP + (D / 2) * N;                // (N/8)*D*4 u32 tiled pairs
  float* bs2 = (float*)(WhB + (N / 8) * D * 4);         // N (log2-domain bias)
  unsigned int* ap2 = (unsigned int*)(bs2 + N);         // D/2

  wh_kernel<<<N / 4, 512, 0, stream>>>(H, W, a, Whh, WhP, WhB, bs2, ap2);
  attn_kernel<<<N / TI, BLK, 0, stream>>>(Whh, WhP, WhB, bs2, ap2, out);
}